// Round 12
// baseline (510.562 us; speedup 1.0000x reference)
//
#include <hip/hip_runtime.h>

#define DIMK 512
#define NBLK 64
#define NTOK 32768

typedef short  short8 __attribute__((ext_vector_type(8)));
typedef float  f32x4  __attribute__((ext_vector_type(4)));
typedef unsigned short u16x8 __attribute__((ext_vector_type(8)));

__device__ __forceinline__ unsigned short f2bf(float f) {
  union { float f; unsigned u; } v; v.f = f;
  unsigned r = (v.u + 0x7FFFu + ((v.u >> 16) & 1u)) >> 16;   // RNE
  return (unsigned short)r;
}
__device__ __forceinline__ float bf2f(unsigned short h) {
  return __uint_as_float(((unsigned)h) << 16);
}

// async 16B global -> LDS (wave-uniform base + lane*16)
__device__ __forceinline__ void gload_lds16(const unsigned short* g,
                                            unsigned short* l) {
  __builtin_amdgcn_global_load_lds(
      (const __attribute__((address_space(1))) unsigned int*)(g),
      (__attribute__((address_space(3))) unsigned int*)(l),
      16, 0, 0);
}

// LDS bank swizzle (rule 21; verified r3: conflicts 4.59M -> 393K).
// Convention: LDS[chunk p] = G[swz(p)]; swz is an involution, so a direct
// LDS writer placing G-chunk g must write at p = swz(g).
__device__ __forceinline__ int swz(int c) { return c ^ ((c >> 3) & 3); }

// ---------------------------------------------------------------------------
// K-slab tiled layouts (all ushort bf16 bits). kk = k&31 throughout.
//   Xb : [(tok>>7)*16 + (k>>5)] [tok&127] [kk]
//   Wt : [w] [k>>5] [n] [kk]
//   Qb : [(tok>>6)*16 + (k>>5)] [tok&63] [kk]
//   Kb : [(tok>>9)*16 + (d>>5)] [tok&511] [kk]
//   Vt : [tok>>5] [d] [tok&31]
//
// r12: K2+K3 fused into k_attn_fused. P never touches global: after softmax,
// P lives as bf16 in registers (p16, 64 VGPRs); per PV iteration the owning
// wave (wv = it>>2) publishes its 64x32 chunk into the As slot of the
// double-buffer via ds_write at the inverse-swizzle position
// p = row*4 + ((c>>3) ^ ((row>>1)&3)), so the r8-proven fragment reader
// (qx = quad ^ ((l16>>1)&3)) works unchanged. bits/bitpack dropped: softmax
// reads the fp32 mask directly (net-zero traffic; removes the d_out race).
// r11 lesson: cooperative grid.sync gave stale cross-XCD reads — abandoned.
// ---------------------------------------------------------------------------

// ---------------------------------------------------------------------------
// K0 prep: [0,1024) xconv (32-tok slice, LDS repack) | [1024,1216) wt_prep
// ---------------------------------------------------------------------------
__global__ __launch_bounds__(256) void k_prep(
    const float* __restrict__ X,
    const float* __restrict__ dw1, const float* __restrict__ dw2,
    const float* __restrict__ dw3,
    unsigned short* __restrict__ Xb, unsigned short* __restrict__ Wt)
{
  __shared__ __align__(16) unsigned short sbuf[32 * 520];   // 33.3 KB
  const int b = blockIdx.x;
  const int tid = threadIdx.x;
  if (b < 1024) {                       // ---- xconv: toks [b*32, b*32+32) ----
    const size_t t0 = (size_t)b * 32;
#pragma unroll
    for (int r = 0; r < 8; ++r) {
      const int idx = r * 256 + tid;               // 0..2047
      const int tl = idx >> 6;
      const int col = (idx & 63) * 8;
      const float4 a = *(const float4*)&X[(t0 + tl) * 512 + col];
      const float4 c = *(const float4*)&X[(t0 + tl) * 512 + col + 4];
      u16x8 o;
      o[0] = f2bf(a.x); o[1] = f2bf(a.y); o[2] = f2bf(a.z); o[3] = f2bf(a.w);
      o[4] = f2bf(c.x); o[5] = f2bf(c.y); o[6] = f2bf(c.z); o[7] = f2bf(c.w);
      *(u16x8*)&sbuf[tl * 520 + col] = o;
    }
    __syncthreads();
    const int trow = b >> 2;
    const int srow = (b & 3) * 32;
#pragma unroll
    for (int r = 0; r < 8; ++r) {
      const int c = r * 256 + tid;
      const int kt = c >> 7;
      const int cc = c & 127;
      const int tl = cc >> 2, kko = (cc & 3) * 8;
      *(u16x8*)&Xb[((size_t)trow * 16 + kt) * 4096 + (srow + tl) * 32 + kko] =
          *(const u16x8*)&sbuf[tl * 520 + kt * 32 + kko];
    }
  } else {                              // ---- wt_prep ----
    float (*t)[65] = (float(*)[65])sbuf;
    const int bb = b - 1024;
    const int w = bb >> 6;              // 0..2
    const int tt = bb & 63;
    const int kt = (tt >> 3) * 64;
    const int nt = (tt & 7) * 64;
    const float* dw = (w == 0) ? dw1 : (w == 1) ? dw2 : dw3;
    const int rr = tid >> 4;
    const int cc = (tid & 15) << 2;
#pragma unroll
    for (int p = 0; p < 4; ++p) {
      const int r = rr + p * 16;
      const float4 v = *(const float4*)&dw[(size_t)(kt + r) * 512 + nt + cc];
      t[cc + 0][r] = v.x; t[cc + 1][r] = v.y;
      t[cc + 2][r] = v.z; t[cc + 3][r] = v.w;
    }
    __syncthreads();
#pragma unroll
    for (int p = 0; p < 4; ++p) {
      const int r = rr + p * 16;
      const int n = nt + r;
      const int k = kt + cc;
      ushort4 o;
      o.x = f2bf(t[r][cc + 0]); o.y = f2bf(t[r][cc + 1]);
      o.z = f2bf(t[r][cc + 2]); o.w = f2bf(t[r][cc + 3]);
      *(ushort4*)&Wt[(size_t)w * 262144 + (size_t)(k >> 5) * 16384 +
                     (size_t)n * 32 + (k & 31)] = o;
    }
  }
}

// ---------------------------------------------------------------------------
// K1: merged QKV (r8-proven, unchanged: 59.6 us / 393K conflicts).
// ---------------------------------------------------------------------------
__global__ __launch_bounds__(256, 2) void k_qkv(
    const unsigned short* __restrict__ Xb, const unsigned short* __restrict__ Wt,
    const float* __restrict__ db1, const float* __restrict__ db2,
    const float* __restrict__ db3,
    unsigned short* __restrict__ Qb, unsigned short* __restrict__ Kb,
    unsigned short* __restrict__ Vt)
{
  __shared__ __align__(16) unsigned short smem[32768];   // 64 KB, 2 buffers

  const int id = blockIdx.x;
  const int x = id & 7, j = id >> 3;
  const int mtile = x * 32 + (j >> 2);
  const int nt = j & 3;
  const int m0 = mtile * 128;
  const int n0 = nt * 128;

  const int tid = threadIdx.x, lane = tid & 63, wv = tid >> 6;
  const int quad = lane >> 4, l16 = lane & 15;
  const int qx = quad ^ ((l16 >> 1) & 3);
  const int rb = (wv >> 1) * 64, cb = (wv & 1) * 64;

  f32x4 acc[3][4][4];
#pragma unroll
  for (int w = 0; w < 3; ++w)
#pragma unroll
    for (int i = 0; i < 4; ++i)
#pragma unroll
      for (int jj = 0; jj < 4; ++jj) {
        f32x4 z = {0.f, 0.f, 0.f, 0.f}; acc[w][i][jj] = z;
      }

  auto stage = [&](unsigned short* base, int it) {
    const unsigned short* aslab = Xb + ((size_t)mtile * 16 + it) * 4096;
    gload_lds16(aslab + swz(tid) * 8, base + tid * 8);
    gload_lds16(aslab + swz(tid + 256) * 8, base + (tid + 256) * 8);
#pragma unroll
    for (int h = 0; h < 6; ++h) {
      const int c = tid + h * 256;
      const int w = c >> 9, cc = c & 511;
      const unsigned short* bslab =
          Wt + (size_t)w * 262144 + (size_t)it * 16384 + (size_t)n0 * 32;
      gload_lds16(bslab + swz(cc) * 8, base + 4096 + w * 4096 + cc * 8);
    }
  };

  stage(smem, 0);
  __syncthreads();
  int cur = 0;
  for (int it = 0; it < 16; ++it) {
    unsigned short* cbuf = smem + cur * 16384;
    if (it < 15) stage(smem + (cur ^ 1) * 16384, it + 1);
    const unsigned short* As = cbuf;
    const unsigned short* Bs = cbuf + 4096;
    short8 af[4];
#pragma unroll
    for (int i = 0; i < 4; ++i)
      af[i] = *(const short8*)&As[(rb + i * 16 + l16) * 32 + qx * 8];
#pragma unroll
    for (int jj = 0; jj < 4; ++jj)
#pragma unroll
      for (int w = 0; w < 3; ++w) {
        const short8 bf =
            *(const short8*)&Bs[w * 4096 + (cb + jj * 16 + l16) * 32 + qx * 8];
#pragma unroll
        for (int i = 0; i < 4; ++i)
          acc[w][i][jj] = __builtin_amdgcn_mfma_f32_16x16x32_bf16(
              af[i], bf, acc[w][i][jj], 0, 0, 0);
      }
    __syncthreads();
    cur ^= 1;
  }

  // ---- epilogue: Q, K tiled stores (direct; r4-proven) ----
#pragma unroll
  for (int i = 0; i < 4; ++i)
#pragma unroll
    for (int jj = 0; jj < 4; ++jj)
#pragma unroll
      for (int r = 0; r < 4; ++r) {
        const int tok = m0 + rb + i * 16 + quad * 4 + r;
        const int col = n0 + cb + jj * 16 + l16;
        Qb[((size_t)(tok >> 6) * 16 + (col >> 5)) * 2048 +
           (tok & 63) * 32 + (col & 31)] = f2bf(acc[0][i][jj][r] + db1[col]);
        Kb[((size_t)(tok >> 9) * 16 + (col >> 5)) * 16384 +
           (tok & 511) * 32 + (col & 31)] = f2bf(acc[1][i][jj][r] + db2[col]);
      }
  // ---- V: LDS transpose (L[col][tok], stride 136) then tiled 16B stores ----
#pragma unroll
  for (int i = 0; i < 4; ++i)
#pragma unroll
    for (int jj = 0; jj < 4; ++jj) {
      const int cl = cb + jj * 16 + l16;
      const int t0 = rb + i * 16 + quad * 4;
      const float bv = db3[n0 + cl];
      ushort4 pk;
      pk.x = f2bf(acc[2][i][jj][0] + bv);
      pk.y = f2bf(acc[2][i][jj][1] + bv);
      pk.z = f2bf(acc[2][i][jj][2] + bv);
      pk.w = f2bf(acc[2][i][jj][3] + bv);
      *(ushort4*)&smem[cl * 136 + t0] = pk;
    }
  __syncthreads();
#pragma unroll
  for (int h = 0; h < 8; ++h) {
    const int c = tid + h * 256;
    const int cl = c >> 4, toff = (c & 15) * 8;
    const int tg = mtile * 128 + toff;
    *(u16x8*)&Vt[(size_t)(tg >> 5) * 16384 + (size_t)(n0 + cl) * 32 +
                 (tg & 31)] = *(const u16x8*)&smem[cl * 136 + toff];
  }
}

// ---------------------------------------------------------------------------
// K2: fused scores + mask + softmax + PV + residual + LayerNorm.
// 256 thr, grid 512 (2 blocks/CU), XCD-aligned decode. QK phase and PV phase
// are the r8-proven loops; P transits LDS (per-iteration chunk publication by
// the owning wave) instead of global. Mask read directly (fp32).
// ---------------------------------------------------------------------------
__global__ __launch_bounds__(256, 2) void k_attn_fused(
    const unsigned short* __restrict__ Qb, const unsigned short* __restrict__ Kb,
    const unsigned short* __restrict__ Vt, const unsigned short* __restrict__ Xb,
    const float* __restrict__ mask, float* __restrict__ Out)
{
  __shared__ __align__(16) unsigned short smem[36864];   // 72 KB, 2 buffers
  __shared__ float  redf[4][64];
  __shared__ float2 red2[4][64];
  const int tid = threadIdx.x, lane = tid & 63, wv = tid >> 6;
  const int quad = lane >> 4, l16 = lane & 15;
  const int qx = quad ^ ((l16 >> 1) & 3);
  const int id = blockIdx.x;
  const int blk = (id & 7) * 8 + ((id >> 3) & 7);   // XCD(id)=id&7 == blk>>3
  const int mt = id >> 6;
  const size_t q0 = (size_t)blk * 512 + (size_t)mt * 64;
  const int qt = blk * 8 + mt;                 // q0 >> 6

  // ======== QK^T ========
  f32x4 acc[4][8];
#pragma unroll
  for (int i = 0; i < 4; ++i)
#pragma unroll
    for (int j = 0; j < 8; ++j) { f32x4 z = {0.f, 0.f, 0.f, 0.f}; acc[i][j] = z; }

  auto stageQK = [&](unsigned short* base, int it) {
    const unsigned short* aslab = Qb + ((size_t)qt * 16 + it) * 2048;
    gload_lds16(aslab + swz(tid) * 8, base + tid * 8);
    const unsigned short* bslab = Kb + ((size_t)blk * 16 + it) * 16384;
#pragma unroll
    for (int h = 0; h < 8; ++h) {
      const int c = tid + h * 256;
      gload_lds16(bslab + swz(c) * 8, base + 2048 + c * 8);
    }
  };

  stageQK(smem, 0);
  __syncthreads();
  int cur = 0;
  for (int it = 0; it < 16; ++it) {
    unsigned short* cbuf = smem + cur * 18432;
    if (it < 15) stageQK(smem + (cur ^ 1) * 18432, it + 1);
    const unsigned short* As = cbuf;
    const unsigned short* Bs = cbuf + 2048;
    short8 af[4], bfv[8];
#pragma unroll
    for (int i = 0; i < 4; ++i)
      af[i] = *(const short8*)&As[(i * 16 + l16) * 32 + qx * 8];
#pragma unroll
    for (int j = 0; j < 8; ++j)
      bfv[j] = *(const short8*)&Bs[(wv * 128 + j * 16 + l16) * 32 + qx * 8];
#pragma unroll
    for (int i = 0; i < 4; ++i)
#pragma unroll
      for (int j = 0; j < 8; ++j)
        acc[i][j] = __builtin_amdgcn_mfma_f32_16x16x32_bf16(
            af[i], bfv[j], acc[i][j], 0, 0, 0);
    __syncthreads();
    cur ^= 1;
  }

  // ======== mask + softmax (direct fp32 mask read) ========
  const float scale = 0.04419417382415922f;   // 1/sqrt(512)
  float rmax[4][4];
#pragma unroll
  for (int i = 0; i < 4; ++i)
#pragma unroll
    for (int r = 0; r < 4; ++r) rmax[i][r] = -3.0e38f;
#pragma unroll
  for (int i = 0; i < 4; ++i)
#pragma unroll
    for (int r = 0; r < 4; ++r) {
      const size_t tok = q0 + i * 16 + quad * 4 + r;
#pragma unroll
      for (int j = 0; j < 8; ++j) {
        const int col = wv * 128 + j * 16 + l16;
        const float mv = mask[tok * (size_t)DIMK + col];
        const float bias = (mv > 0.5f) ? 0.0f : -1e10f;
        const float v = acc[i][j][r] * scale + bias;
        acc[i][j][r] = v;
        rmax[i][r] = fmaxf(rmax[i][r], v);
      }
    }
#pragma unroll
  for (int i = 0; i < 4; ++i)
#pragma unroll
    for (int r = 0; r < 4; ++r)
      for (int d = 1; d < 16; d <<= 1)
        rmax[i][r] = fmaxf(rmax[i][r], __shfl_xor(rmax[i][r], d, 64));
  if (l16 == 0)
#pragma unroll
    for (int i = 0; i < 4; ++i)
#pragma unroll
      for (int r = 0; r < 4; ++r) redf[wv][i * 16 + quad * 4 + r] = rmax[i][r];
  __syncthreads();
#pragma unroll
  for (int i = 0; i < 4; ++i)
#pragma unroll
    for (int r = 0; r < 4; ++r) {
      const int row = i * 16 + quad * 4 + r;
      rmax[i][r] = fmaxf(fmaxf(redf[0][row], redf[1][row]),
                         fmaxf(redf[2][row], redf[3][row]));
    }
  __syncthreads();
  float rsum[4][4];
#pragma unroll
  for (int i = 0; i < 4; ++i)
#pragma unroll
    for (int r = 0; r < 4; ++r) rsum[i][r] = 0.f;
#pragma unroll
  for (int i = 0; i < 4; ++i)
#pragma unroll
    for (int j = 0; j < 8; ++j)
#pragma unroll
      for (int r = 0; r < 4; ++r) {
        const float e = __expf(acc[i][j][r] - rmax[i][r]);
        acc[i][j][r] = e;
        rsum[i][r] += e;
      }
#pragma unroll
  for (int i = 0; i < 4; ++i)
#pragma unroll
    for (int r = 0; r < 4; ++r)
      for (int d = 1; d < 16; d <<= 1)
        rsum[i][r] += __shfl_xor(rsum[i][r], d, 64);
  if (l16 == 0)
#pragma unroll
    for (int i = 0; i < 4; ++i)
#pragma unroll
      for (int r = 0; r < 4; ++r) redf[wv][i * 16 + quad * 4 + r] = rsum[i][r];
  __syncthreads();
#pragma unroll
  for (int i = 0; i < 4; ++i)
#pragma unroll
    for (int r = 0; r < 4; ++r) {
      const int row = i * 16 + quad * 4 + r;
      rsum[i][r] = 1.0f / (redf[0][row] + redf[1][row] +
                           redf[2][row] + redf[3][row]);
    }

  // ======== P -> bf16 registers (QK acc dies here) ========
  unsigned p16[4][8][2];
#pragma unroll
  for (int i = 0; i < 4; ++i)
#pragma unroll
    for (int j = 0; j < 8; ++j) {
      p16[i][j][0] = (unsigned)f2bf(acc[i][j][0] * rsum[i][0]) |
                     ((unsigned)f2bf(acc[i][j][1] * rsum[i][1]) << 16);
      p16[i][j][1] = (unsigned)f2bf(acc[i][j][2] * rsum[i][2]) |
                     ((unsigned)f2bf(acc[i][j][3] * rsum[i][3]) << 16);
    }

  // ======== PV (P via LDS chunk publication; V staged from global) ========
  f32x4 acc2[4][8];
#pragma unroll
  for (int i = 0; i < 4; ++i)
#pragma unroll
    for (int j = 0; j < 8; ++j) { f32x4 z = {0.f, 0.f, 0.f, 0.f}; acc2[i][j] = z; }

  auto stageV = [&](unsigned short* base, int it) {
    const unsigned short* bslab = Vt + ((size_t)blk * 16 + it) * 16384;
#pragma unroll
    for (int h = 0; h < 8; ++h) {
      const int c = tid + h * 256;
      gload_lds16(bslab + swz(c) * 8, base + 2048 + c * 8);
    }
  };
  // owner wave (wv == it>>2) writes its 64x32 P chunk into the As slot at the
  // inverse-swizzle position so the standard qx reader sees G-chunk row*4+quad.
  auto pubP = [&](unsigned short* base, int it) {
    if (wv == (it >> 2)) {
#pragma unroll
      for (int e = 0; e < 2; ++e) {
        const int j = (it & 3) * 2 + e;
#pragma unroll
        for (int i = 0; i < 4; ++i)
#pragma unroll
          for (int r = 0; r < 4; ++r) {
            const int row = i * 16 + quad * 4 + r;
            const int c = e * 16 + l16;
            const int p = row * 4 + (((c >> 3) ^ (row >> 1)) & 3);
            const unsigned v = p16[i][j][r >> 1];
            base[p * 8 + (c & 7)] =
                (unsigned short)((r & 1) ? (v >> 16) : (v & 0xFFFFu));
          }
      }
    }
  };

  stageV(smem, 0);
  pubP(smem, 0);
  __syncthreads();
#pragma unroll
  for (int it = 0; it < 16; ++it) {
    unsigned short* cbuf = smem + (it & 1) * 18432;
    if (it < 15) {
      unsigned short* nbuf = smem + ((it & 1) ^ 1) * 18432;
      stageV(nbuf, it + 1);
      pubP(nbuf, it + 1);
    }
    const unsigned short* As = cbuf;
    const unsigned short* Bs = cbuf + 2048;
    short8 af[4], bfv[8];
#pragma unroll
    for (int i = 0; i < 4; ++i)
      af[i] = *(const short8*)&As[(i * 16 + l16) * 32 + qx * 8];
#pragma unroll
    for (int j = 0; j < 8; ++j)
      bfv[j] = *(const short8*)&Bs[(wv * 128 + j * 16 + l16) * 32 + qx * 8];
#pragma unroll
    for (int i = 0; i < 4; ++i)
#pragma unroll
      for (int j = 0; j < 8; ++j)
        acc2[i][j] = __builtin_amdgcn_mfma_f32_16x16x32_bf16(
            af[i], bfv[j], acc2[i][j], 0, 0, 0);
    __syncthreads();
  }

  // ======== residual + LayerNorm + Out repack (r8-proven) ========
  float vsum[4][4], vsq[4][4];
#pragma unroll
  for (int i = 0; i < 4; ++i)
#pragma unroll
    for (int r = 0; r < 4; ++r) { vsum[i][r] = 0.f; vsq[i][r] = 0.f; }
#pragma unroll
  for (int i = 0; i < 4; ++i)
#pragma unroll
    for (int j = 0; j < 8; ++j)
#pragma unroll
      for (int r = 0; r < 4; ++r) {
        const int tok = (int)(q0 + i * 16 + quad * 4 + r);
        const int col = wv * 128 + j * 16 + l16;
        const float v = acc2[i][j][r] +
            bf2f(Xb[((size_t)(tok >> 7) * 16 + (col >> 5)) * 4096 +
                    (tok & 127) * 32 + (col & 31)]);
        acc2[i][j][r] = v;
        vsum[i][r] += v;
        vsq[i][r] += v * v;
      }
#pragma unroll
  for (int i = 0; i < 4; ++i)
#pragma unroll
    for (int r = 0; r < 4; ++r)
      for (int d = 1; d < 16; d <<= 1) {
        vsum[i][r] += __shfl_xor(vsum[i][r], d, 64);
        vsq[i][r]  += __shfl_xor(vsq[i][r], d, 64);
      }
  if (l16 == 0)
#pragma unroll
    for (int i = 0; i < 4; ++i)
#pragma unroll
      for (int r = 0; r < 4; ++r) {
        float2 p; p.x = vsum[i][r]; p.y = vsq[i][r];
        red2[wv][i * 16 + quad * 4 + r] = p;
      }
  __syncthreads();
#pragma unroll
  for (int i = 0; i < 4; ++i)
#pragma unroll
    for (int r = 0; r < 4; ++r) {
      const int row = i * 16 + quad * 4 + r;
      float s = 0.f, q = 0.f;
#pragma unroll
      for (int w = 0; w < 4; ++w) { s += red2[w][row].x; q += red2[w][row].y; }
      const float mean = s * (1.0f / 512.0f);
      const float var  = q * (1.0f / 512.0f) - mean * mean;
      vsum[i][r] = mean;
      vsq[i][r]  = rsqrtf(var + 1e-3f);
    }
  // Out repack: float L[64][260] (66.5 KB), two col-halves -> float4 stores
  float* L = (float*)smem;
#pragma unroll
  for (int p = 0; p < 2; ++p) {
    __syncthreads();
    if ((wv >> 1) == p) {
#pragma unroll
      for (int i = 0; i < 4; ++i)
#pragma unroll
        for (int j = 0; j < 8; ++j) {
          const int cl = (wv & 1) * 128 + j * 16 + l16;
          const int t0 = i * 16 + quad * 4;
#pragma unroll
          for (int r = 0; r < 4; ++r)
            L[(t0 + r) * 260 + cl] = (acc2[i][j][r] - vsum[i][r]) * vsq[i][r];
        }
    }
    __syncthreads();
#pragma unroll
    for (int h = 0; h < 16; ++h) {
      const int c = tid + h * 256;
      const int tl = c >> 6, c0 = (c & 63) * 4;
      const float4 v = *(const float4*)&L[tl * 260 + c0];
      *(float4*)&Out[(q0 + tl) * (size_t)DIMK + p * 256 + c0] = v;
    }
  }
}

// ---------------------------------------------------------------------------
extern "C" void kernel_launch(void* const* d_in, const int* in_sizes, int n_in,
                              void* d_out, int out_size, void* d_ws, size_t ws_size,
                              hipStream_t stream)
{
  const float* X    = (const float*)d_in[0];
  const float* mask = (const float*)d_in[1];
  const float* dw1  = (const float*)d_in[2];
  const float* dw2  = (const float*)d_in[3];
  const float* dw3  = (const float*)d_in[4];
  const float* db1  = (const float*)d_in[5];
  const float* db2  = (const float*)d_in[6];
  const float* db3  = (const float*)d_in[7];
  float* Out = (float*)d_out;

  char* ws = (char*)d_ws;
  const size_t MB = 1ull << 20;
  // ws (130 MB): [Wt 2 | Qb 32 | Kb 32 | Vt 32 | Xb 32]. No bits buffer:
  // mask is read directly by k_attn_fused; P never leaves the fused kernel.
  unsigned short* Wt = (unsigned short*)(ws);
  unsigned short* Qb = (unsigned short*)(ws + 2 * MB);
  unsigned short* Kb = (unsigned short*)(ws + 34 * MB);
  unsigned short* Vt = (unsigned short*)(ws + 66 * MB);
  unsigned short* Xb = (unsigned short*)(ws + 98 * MB);

  k_prep       <<<1216, 256, 0, stream>>>(X, dw1, dw2, dw3, Xb, Wt);
  k_qkv        <<<1024, 256, 0, stream>>>(Xb, Wt, db1, db2, db3, Qb, Kb, Vt);
  k_attn_fused <<<512, 256, 0, stream>>>(Qb, Kb, Vt, Xb, mask, Out);
}